// Round 8
// baseline (333.296 us; speedup 1.0000x reference)
//
#include <hip/hip_runtime.h>
#include <hip/hip_fp16.h>
#include <math.h>

#define NROWS 4194304
#define M4Q   (NROWS/4)          // 1048576 4-row groups
#define EPSV  1e-5f

#define BLK   1024
#define THR   256
#define TOT   (BLK*THR)          // 262144 threads
#define GPT   (M4Q/TOT)          // 4 groups per thread

#define SLOTS 64                 // stat partial slots (128 B apart)
#define SSTR  (SLOTS*32)         // floats per stage region
#define STATS_BYTES (9*SSTR*4)   // 72 KB

// fp16 SoA-pair z layout: [c0c1] 16B, [c2c3] 16B, [c4] 8B per group
#define ZAB_OFF 0
#define ZCD_OFF ((size_t)M4Q*16)
#define ZE_OFF  ((size_t)M4Q*32)
#define ZBYTES_H ((size_t)M4Q*40)    // 42 MB

// Stage numbering: 0:x 1:h1 2:z1 3:h2 4:z2 5:h3 6:z3 7:h4 8:z4
// Stats: 20 floats/stage = 5 sums + 15 upper-tri second moments (exact over
// NROWS, computed on the fp16-rounded z values actually used downstream).
// Linear bias cancels inside BN (mean-subtracted): lins_b/lin9_b unused.

struct __align__(8)  h4   { __half2 lo, hi; };
struct __align__(16) h4x2 { h4 a, b; };

__device__ __forceinline__ h4 f4_to_h4(const float4& f){
  h4 r; r.lo = __floats2half2_rn(f.x, f.y); r.hi = __floats2half2_rn(f.z, f.w);
  return r;
}
__device__ __forceinline__ float4 h4_to_f4(const h4& h){
  float2 a = __half22float2(h.lo), b = __half22float2(h.hi);
  return make_float4(a.x, a.y, b.x, b.y);
}

__device__ __forceinline__ float4 mk4(float v){ return make_float4(v,v,v,v); }
__device__ __forceinline__ float4 fma44(float a, const float4& b, const float4& c){
  return make_float4(fmaf(a,b.x,c.x), fmaf(a,b.y,c.y), fmaf(a,b.z,c.z), fmaf(a,b.w,c.w));
}
__device__ __forceinline__ float4 relu4(const float4& a){
  return make_float4(fmaxf(a.x,0.f),fmaxf(a.y,0.f),fmaxf(a.z,0.f),fmaxf(a.w,0.f));
}
// Wave-uniform value -> SGPR (folded constants shouldn't burn VGPRs).
__device__ __forceinline__ float uni(float v){
  return __uint_as_float((unsigned)__builtin_amdgcn_readfirstlane((int)__float_as_uint(v)));
}

__device__ __forceinline__ void z_load(const char* ws, int G, float4 z[5]){
  const h4x2 p01 = ((const h4x2*)(ws + ZAB_OFF))[G];
  const h4x2 p23 = ((const h4x2*)(ws + ZCD_OFF))[G];
  const h4   p4  = ((const h4*)  (ws + ZE_OFF ))[G];
  z[0]=h4_to_f4(p01.a); z[1]=h4_to_f4(p01.b);
  z[2]=h4_to_f4(p23.a); z[3]=h4_to_f4(p23.b);
  z[4]=h4_to_f4(p4);
}
// store fp16 and round z in place (stats see stored values)
__device__ __forceinline__ void z_store(char* ws, int G, float4 z[5]){
  h4x2 p01; p01.a=f4_to_h4(z[0]); p01.b=f4_to_h4(z[1]);
  h4x2 p23; p23.a=f4_to_h4(z[2]); p23.b=f4_to_h4(z[3]);
  h4   p4 = f4_to_h4(z[4]);
  ((h4x2*)(ws + ZAB_OFF))[G]=p01;
  ((h4x2*)(ws + ZCD_OFF))[G]=p23;
  ((h4*)  (ws + ZE_OFF ))[G]=p4;
  z[0]=h4_to_f4(p01.a); z[1]=h4_to_f4(p01.b);
  z[2]=h4_to_f4(p23.a); z[3]=h4_to_f4(p23.b);
  z[4]=h4_to_f4(p4);
}

__device__ __forceinline__ void acc_stats(const float4 z[5], float acc[20]){
  #pragma unroll
  for(int d=0; d<5; ++d) acc[d] += (z[d].x + z[d].y) + (z[d].z + z[d].w);
  int k = 5;
  #pragma unroll
  for(int d=0; d<5; ++d){
    #pragma unroll
    for(int e=d; e<5; ++e){
      acc[k] += z[d].x*z[e].x + z[d].y*z[e].y + z[d].z*z[e].z + z[d].w*z[e].w;
      ++k;
    }
  }
}

// Fold BN(Lin(z)) into affine y = A z + c from raw stats sums (scaled by invN).
__device__ __forceinline__ void fold_generic(const float* __restrict__ sums,
                                             const float* __restrict__ W,
                                             const float* __restrict__ g,
                                             const float* __restrict__ be,
                                             int c, float invN,
                                             float* Arow, float* cout){
  float mu[5];
  #pragma unroll
  for(int d=0;d<5;++d) mu[d] = sums[d]*invN;
  float wr[5];
  #pragma unroll
  for(int d=0;d<5;++d) wr[d] = W[c*5+d];
  float m = 0.f, v = 0.f;
  #pragma unroll
  for(int d=0;d<5;++d){
    m += wr[d]*mu[d];
    #pragma unroll
    for(int e=0;e<5;++e){
      const int dd = d<e?d:e, ee = d<e?e:d;
      const float cov = sums[5 + dd*5+ee - (dd*(dd+1))/2]*invN - mu[d]*mu[e];
      v += wr[d]*wr[e]*cov;
    }
  }
  const float s = g[c] / sqrtf(v + EPSV);
  #pragma unroll
  for(int d=0;d<5;++d) Arow[d] = s*wr[d];
  *cout = be[c] - s*m;
}

// Block-reduce acc[20]; atomicAdd into this block's slot (slots 128 B apart).
__device__ __forceinline__ void reduce_slots(float acc[20], float* stage){
  #pragma unroll
  for(int k=0;k<20;++k){
    float v = acc[k];
    #pragma unroll
    for(int m=32;m>=1;m>>=1) v += __shfl_xor(v, m);
    acc[k] = v;
  }
  __shared__ float red[(THR/64)*20];
  const int lane = threadIdx.x & 63, wv = threadIdx.x >> 6;
  if(lane==0){
    #pragma unroll
    for(int k=0;k<20;++k) red[wv*20+k] = acc[k];
  }
  __syncthreads();
  if(threadIdx.x < 20){
    float s = 0.f;
    #pragma unroll
    for(int w=0; w<THR/64; ++w) s += red[w*20 + threadIdx.x];
    atomicAdd(stage + (blockIdx.x & (SLOTS-1))*32 + threadIdx.x, s);
  }
}

// Gather the slot partials of a stage into raw[20] (LDS).
__device__ __forceinline__ void sum_slots(const float* __restrict__ stage, float* raw){
  if(threadIdx.x < 20){
    float s = 0.f;
    #pragma unroll 8
    for(int j=0;j<SLOTS;++j) s += stage[j*32 + (int)threadIdx.x];
    raw[threadIdx.x] = s;
  }
  __syncthreads();
}

// ---- K1: read x (AoS f32), transpose to fp16 pair-layout, stage-0 stats ----
__global__ __launch_bounds__(THR)
void k_init(const float* __restrict__ x, char* __restrict__ zws,
            float* __restrict__ stats){
  const int tid = blockIdx.x*THR + threadIdx.x;
  float acc[20];
  #pragma unroll
  for(int k=0;k<20;++k) acc[k]=0.f;
  #pragma unroll 2
  for(int g=0; g<GPT; ++g){
    const int G = tid + g*TOT;
    union { float4 v[5]; float f[20]; } u;
    const float4* xp = (const float4*)x + (size_t)G*5;
    #pragma unroll
    for(int q=0;q<5;++q) u.v[q] = xp[q];
    float4 z[5];
    #pragma unroll
    for(int c=0;c<5;++c) z[c] = make_float4(u.f[c], u.f[5+c], u.f[10+c], u.f[15+c]);
    z_store(zws, G, z);
    acc_stats(z, acc);
  }
  reduce_slots(acc, stats + 0*SSTR);
}

// ---- K2 (x4): stats of h = relu(F1 z) ----
__global__ __launch_bounds__(THR)
void k_statsH(const char* __restrict__ zws, float* __restrict__ stats,
              const float* __restrict__ lins_w, const float* __restrict__ bn_g,
              const float* __restrict__ bn_b, int b){
  const int i = 2*b, j = i+1;
  __shared__ float raw[20];
  __shared__ float F1s[30];
  sum_slots(stats + i*SSTR, raw);
  if(threadIdx.x < 5)
    fold_generic(raw, lins_w+25*i, bn_g+5*i, bn_b+5*i, (int)threadIdx.x,
                 1.0f/(float)NROWS, &F1s[threadIdx.x*5], &F1s[25+threadIdx.x]);
  __syncthreads();
  float f1[30];
  #pragma unroll
  for(int k=0;k<30;++k) f1[k] = uni(F1s[k]);
  const int tid = blockIdx.x*THR + threadIdx.x;
  float acc[20];
  #pragma unroll
  for(int k=0;k<20;++k) acc[k]=0.f;
  #pragma unroll 2
  for(int g=0; g<GPT; ++g){
    const int G = tid + g*TOT;
    float4 z[5], h[5];
    z_load(zws, G, z);
    #pragma unroll
    for(int c=0;c<5;++c){
      float4 u = mk4(f1[25+c]);
      #pragma unroll
      for(int d=0;d<5;++d) u = fma44(f1[c*5+d], z[d], u);
      h[c] = relu4(u);
    }
    acc_stats(h, acc);
  }
  reduce_slots(acc, stats + j*SSTR);
}

// ---- K3 (x4): z' = relu(F2 relu(F1 z) + SW z + c'), write z' fp16, stats ----
__global__ __launch_bounds__(THR)
void k_updateZ(char* __restrict__ zws, float* __restrict__ stats,
               const float* __restrict__ lins_w, const float* __restrict__ bn_g,
               const float* __restrict__ bn_b, const float* __restrict__ skips_w,
               const float* __restrict__ skips_b, int b){
  const int i = 2*b, j = i+1;
  __shared__ float rawA[20], rawB[20];
  __shared__ float F1s[30], F2s[30], SWs[25];
  sum_slots(stats + i*SSTR, rawA);
  sum_slots(stats + j*SSTR, rawB);
  if(threadIdx.x < 5){
    fold_generic(rawA, lins_w+25*i, bn_g+5*i, bn_b+5*i, (int)threadIdx.x,
                 1.0f/(float)NROWS, &F1s[threadIdx.x*5], &F1s[25+threadIdx.x]);
    fold_generic(rawB, lins_w+25*j, bn_g+5*j, bn_b+5*j, (int)threadIdx.x,
                 1.0f/(float)NROWS, &F2s[threadIdx.x*5], &F2s[25+threadIdx.x]);
    F2s[25+threadIdx.x] += skips_b[5*b + threadIdx.x];   // merge skip bias
  }
  if(threadIdx.x >= 64 && threadIdx.x < 89)
    SWs[threadIdx.x-64] = skips_w[25*b + (threadIdx.x-64)];
  __syncthreads();
  float f1[30], f2[30], sw[25];
  #pragma unroll
  for(int k=0;k<30;++k){ f1[k]=uni(F1s[k]); f2[k]=uni(F2s[k]); }
  #pragma unroll
  for(int k=0;k<25;++k) sw[k]=uni(SWs[k]);
  const int tid = blockIdx.x*THR + threadIdx.x;
  float acc[20];
  #pragma unroll
  for(int k=0;k<20;++k) acc[k]=0.f;
  #pragma unroll 2
  for(int g=0; g<GPT; ++g){
    const int G = tid + g*TOT;
    float4 z[5], h[5], t[5];
    z_load(zws, G, z);
    #pragma unroll
    for(int c=0;c<5;++c){
      float4 u = mk4(f1[25+c]);
      #pragma unroll
      for(int d=0;d<5;++d) u = fma44(f1[c*5+d], z[d], u);
      h[c] = relu4(u);
    }
    #pragma unroll
    for(int c=0;c<5;++c){
      float4 u = mk4(f2[25+c]);
      #pragma unroll
      for(int d=0;d<5;++d){
        u = fma44(f2[c*5+d], h[d], u);
        u = fma44(sw[c*5+d], z[d], u);
      }
      t[c] = relu4(u);
    }
    z_store(zws, G, t);
    acc_stats(t, acc);
  }
  reduce_slots(acc, stats + (i+2)*SSTR);
}

// ---- K4: fold lin9+bn9, apply lin10, write out (f32) ----
__global__ __launch_bounds__(THR)
void k_final(const char* __restrict__ zws, const float* __restrict__ stats,
             const float* __restrict__ lin9_w, const float* __restrict__ bn9_g,
             const float* __restrict__ bn9_b, const float* __restrict__ lin10_w,
             const float* __restrict__ lin10_b, float* __restrict__ out){
  __shared__ float raw[20];
  __shared__ float A9c[12];
  sum_slots(stats + 8*SSTR, raw);
  if(threadIdx.x < 2)
    fold_generic(raw, lin9_w, bn9_g, bn9_b, (int)threadIdx.x,
                 1.0f/(float)NROWS, &A9c[threadIdx.x*5], &A9c[10+threadIdx.x]);
  __syncthreads();
  float f9[12];
  #pragma unroll
  for(int k=0;k<12;++k) f9[k] = uni(A9c[k]);
  const float w10a = uni(lin10_w[0]), w10b = uni(lin10_w[1]), b10 = uni(lin10_b[0]);
  const int tid = blockIdx.x*THR + threadIdx.x;
  #pragma unroll 2
  for(int g=0; g<GPT; ++g){
    const int G = tid + g*TOT;
    float4 z[5];
    z_load(zws, G, z);
    float4 u0 = mk4(f9[10]), u1 = mk4(f9[11]);
    #pragma unroll
    for(int d=0;d<5;++d){ u0 = fma44(f9[d], z[d], u0); u1 = fma44(f9[5+d], z[d], u1); }
    u0 = relu4(u0); u1 = relu4(u1);
    float4 o = mk4(b10);
    o = fma44(w10a, u0, o);
    o = fma44(w10b, u1, o);
    ((float4*)out)[G] = o;
  }
}

// ---- fallback (tiny ws): exact full-data recompute-from-x chain, f32 ----
__global__ __launch_bounds__(THR)
void k_fromx(const float* __restrict__ x, float* __restrict__ stats,
             const float* __restrict__ lins_w, const float* __restrict__ bn_g,
             const float* __restrict__ bn_b, const float* __restrict__ skips_w,
             const float* __restrict__ skips_b, const float* __restrict__ lin9_w,
             const float* __restrict__ bn9_g, const float* __restrict__ bn9_b,
             const float* __restrict__ lin10_w, const float* __restrict__ lin10_b,
             float* __restrict__ out, int target, int do_final){
  __shared__ float rawAll[9][20];
  __shared__ float FA[8][30];
  __shared__ float SW[100];
  __shared__ float A9c[12];
  const int tix = threadIdx.x;
  const int nf = do_final ? 9 : target;
  if(tix < 20*nf){
    const int L = tix/20, k = tix%20;
    float s = 0.f;
    #pragma unroll 8
    for(int j=0;j<SLOTS;++j) s += stats[L*SSTR + j*32 + k];
    rawAll[L][k] = s;
  }
  __syncthreads();
  const int nlay = do_final ? 8 : (target < 8 ? target : 8);
  if(tix < 5*nlay){
    const int L = tix/5, c = tix%5;
    fold_generic(&rawAll[L][0], lins_w+25*L, bn_g+5*L, bn_b+5*L, c,
                 1.0f/(float)NROWS, &FA[L][c*5], &FA[L][25+c]);
    if(L & 1) FA[L][25+c] += skips_b[(L>>1)*5 + c];
  } else if(tix >= 64 && tix < 164){
    SW[tix-64] = skips_w[tix-64];
  }
  if(do_final && tix >= 40 && tix < 42){
    const int c = tix-40;
    fold_generic(&rawAll[8][0], lin9_w, bn9_g, bn9_b, c,
                 1.0f/(float)NROWS, &A9c[c*5], &A9c[10+c]);
  }
  __syncthreads();
  float w10a=0.f, w10b=0.f, b10=0.f;
  if(do_final){ w10a = lin10_w[0]; w10b = lin10_w[1]; b10 = lin10_b[0]; }
  float acc[20];
  #pragma unroll
  for(int k=0;k<20;++k) acc[k]=0.f;
  const int gid = blockIdx.x*THR + tix;
  const int steps = do_final ? 8 : target;
  for(int t0=gid; t0<M4Q; t0+=TOT){
    union { float4 v[5]; float f[20]; } u;
    const float4* xp = (const float4*)x + (size_t)t0*5;
    #pragma unroll
    for(int q=0;q<5;++q) u.v[q] = xp[q];
    float4 z[5], h[5];
    #pragma unroll
    for(int c=0;c<5;++c) z[c] = make_float4(u.f[c], u.f[5+c], u.f[10+c], u.f[15+c]);
    #pragma unroll 1
    for(int s=1; s<=steps; ++s){
      const int L = s-1, b = L>>1;
      if(s & 1){
        #pragma unroll
        for(int c=0;c<5;++c){
          float4 t2 = mk4(FA[L][25+c]);
          #pragma unroll
          for(int d=0;d<5;++d) t2 = fma44(FA[L][c*5+d], z[d], t2);
          h[c] = relu4(t2);
        }
      } else {
        float4 zn[5];
        #pragma unroll
        for(int c=0;c<5;++c){
          float4 t2 = mk4(FA[L][25+c]);
          #pragma unroll
          for(int d=0;d<5;++d){
            t2 = fma44(FA[L][c*5+d], h[d], t2);
            t2 = fma44(SW[b*25+c*5+d], z[d], t2);
          }
          zn[c] = relu4(t2);
        }
        #pragma unroll
        for(int c=0;c<5;++c) z[c] = zn[c];
      }
    }
    if(do_final){
      float4 u0 = mk4(A9c[10]), u1 = mk4(A9c[11]);
      #pragma unroll
      for(int d=0;d<5;++d){ u0 = fma44(A9c[d], z[d], u0); u1 = fma44(A9c[5+d], z[d], u1); }
      u0 = relu4(u0); u1 = relu4(u1);
      float4 o = mk4(b10);
      o = fma44(w10a, u0, o);
      o = fma44(w10b, u1, o);
      ((float4*)out)[t0] = o;
    } else {
      if(steps & 1) acc_stats(h, acc);
      else          acc_stats(z, acc);
    }
  }
  if(!do_final) reduce_slots(acc, stats + target*SSTR);
}

extern "C" void kernel_launch(void* const* d_in, const int* in_sizes, int n_in,
                              void* d_out, int out_size, void* d_ws, size_t ws_size,
                              hipStream_t stream){
  (void)in_sizes; (void)n_in; (void)out_size;
  const float* x       = (const float*)d_in[0];
  const float* lins_w  = (const float*)d_in[1];
  // d_in[2] = lins_b: cancels inside BN, unused
  const float* skips_w = (const float*)d_in[3];
  const float* skips_b = (const float*)d_in[4];
  const float* bn_g    = (const float*)d_in[5];
  const float* bn_b    = (const float*)d_in[6];
  const float* lin9_w  = (const float*)d_in[7];
  // d_in[8] = lin9_b: cancels inside BN, unused
  const float* bn9_g   = (const float*)d_in[9];
  const float* bn9_b   = (const float*)d_in[10];
  const float* lin10_w = (const float*)d_in[11];
  const float* lin10_b = (const float*)d_in[12];
  float* out = (float*)d_out;

  if(ws_size >= ZBYTES_H + (size_t)STATS_BYTES){
    char*  zws   = (char*)d_ws;
    float* stats = (float*)((char*)d_ws + ZBYTES_H);
    hipMemsetAsync(stats, 0, STATS_BYTES, stream);
    k_init<<<BLK, THR, 0, stream>>>(x, zws, stats);
    for(int b=0;b<4;++b){
      k_statsH <<<BLK, THR, 0, stream>>>(zws, stats, lins_w, bn_g, bn_b, b);
      k_updateZ<<<BLK, THR, 0, stream>>>(zws, stats, lins_w, bn_g, bn_b,
                                         skips_w, skips_b, b);
    }
    k_final<<<BLK, THR, 0, stream>>>(zws, stats, lin9_w, bn9_g, bn9_b,
                                     lin10_w, lin10_b, out);
  } else {
    float* stats = (float*)d_ws;
    hipMemsetAsync(stats, 0, STATS_BYTES, stream);
    for(int s=0; s<=8; ++s)
      k_fromx<<<BLK, THR, 0, stream>>>(x, stats, lins_w, bn_g, bn_b, skips_w,
                                       skips_b, lin9_w, bn9_g, bn9_b, lin10_w,
                                       lin10_b, out, s, 0);
    k_fromx<<<BLK, THR, 0, stream>>>(x, stats, lins_w, bn_g, bn_b, skips_w,
                                     skips_b, lin9_w, bn9_g, bn9_b, lin10_w,
                                     lin10_b, out, 8, 1);
  }
}

// Round 9
// 313.157 us; speedup vs baseline: 1.0643x; 1.0643x over previous
//
#include <hip/hip_runtime.h>
#include <hip/hip_fp16.h>
#include <math.h>

#define NROWS 4194304
#define M4Q   (NROWS/4)          // 1048576 float4-groups
#define EPSV  1e-5f

#define BLK   512
#define THR   256
#define TOT   (BLK*THR)          // 131072 threads
#define GPT   (M4Q/TOT)          // 8 float4-groups per thread

#define SLOTS 32                 // stat partial slots (128 B apart)
#define SSTR  (SLOTS*32)         // floats per stage region
#define STATS_BYTES (9*SSTR*4)   // 36 KB
#define ZBYTES_H ((size_t)5*M4Q*8)   // fp16 SoA z-buffer: 42 MB

// Stage numbering: 0:x 1:h1 2:z1 3:h2 4:z2 5:h3 6:z3 7:h4 8:z4
// Stats: 20 floats/stage = 5 sums + 15 upper-tri second moments (exact, NROWS,
// computed on the fp16-rounded z values actually used downstream).
// Linear bias cancels inside BN (mean-subtracted): lins_b/lin9_b unused.
//
// R8 lesson: 1024x4 config + split-pair layout + readfirstlane regressed 3%;
// this is the best-measured R7 configuration (512x8, per-component h4 SoA).

struct __align__(8) h4 { __half2 lo, hi; };

__device__ __forceinline__ h4 f4_to_h4(const float4& f){
  h4 r; r.lo = __floats2half2_rn(f.x, f.y); r.hi = __floats2half2_rn(f.z, f.w);
  return r;
}
__device__ __forceinline__ float4 h4_to_f4(const h4& h){
  float2 a = __half22float2(h.lo), b = __half22float2(h.hi);
  return make_float4(a.x, a.y, b.x, b.y);
}

__device__ __forceinline__ float4 mk4(float v){ return make_float4(v,v,v,v); }
__device__ __forceinline__ float4 fma44(float a, const float4& b, const float4& c){
  return make_float4(fmaf(a,b.x,c.x), fmaf(a,b.y,c.y), fmaf(a,b.z,c.z), fmaf(a,b.w,c.w));
}
__device__ __forceinline__ float4 relu4(const float4& a){
  return make_float4(fmaxf(a.x,0.f),fmaxf(a.y,0.f),fmaxf(a.z,0.f),fmaxf(a.w,0.f));
}

__device__ __forceinline__ void acc_stats(const float4 z[5], float acc[20]){
  #pragma unroll
  for(int d=0; d<5; ++d) acc[d] += (z[d].x + z[d].y) + (z[d].z + z[d].w);
  int k = 5;
  #pragma unroll
  for(int d=0; d<5; ++d){
    #pragma unroll
    for(int e=d; e<5; ++e){
      acc[k] += z[d].x*z[e].x + z[d].y*z[e].y + z[d].z*z[e].z + z[d].w*z[e].w;
      ++k;
    }
  }
}

// Fold BN(Lin(z)) into affine y = A z + c from raw stats sums (scaled by invN).
__device__ __forceinline__ void fold_generic(const float* __restrict__ sums,
                                             const float* __restrict__ W,
                                             const float* __restrict__ g,
                                             const float* __restrict__ be,
                                             int c, float invN,
                                             float* Arow, float* cout){
  float mu[5];
  #pragma unroll
  for(int d=0;d<5;++d) mu[d] = sums[d]*invN;
  float wr[5];
  #pragma unroll
  for(int d=0;d<5;++d) wr[d] = W[c*5+d];
  float m = 0.f, v = 0.f;
  #pragma unroll
  for(int d=0;d<5;++d){
    m += wr[d]*mu[d];
    #pragma unroll
    for(int e=0;e<5;++e){
      const int dd = d<e?d:e, ee = d<e?e:d;
      const float cov = sums[5 + dd*5+ee - (dd*(dd+1))/2]*invN - mu[d]*mu[e];
      v += wr[d]*wr[e]*cov;
    }
  }
  const float s = g[c] / sqrtf(v + EPSV);
  #pragma unroll
  for(int d=0;d<5;++d) Arow[d] = s*wr[d];
  *cout = be[c] - s*m;
}

// Block-reduce acc[20]; atomicAdd into this block's slot (slots 128 B apart).
__device__ __forceinline__ void reduce_slots(float acc[20], float* stage){
  #pragma unroll
  for(int k=0;k<20;++k){
    float v = acc[k];
    #pragma unroll
    for(int m=32;m>=1;m>>=1) v += __shfl_xor(v, m);
    acc[k] = v;
  }
  __shared__ float red[(THR/64)*20];
  const int lane = threadIdx.x & 63, wv = threadIdx.x >> 6;
  if(lane==0){
    #pragma unroll
    for(int k=0;k<20;++k) red[wv*20+k] = acc[k];
  }
  __syncthreads();
  if(threadIdx.x < 20){
    float s = 0.f;
    #pragma unroll
    for(int w=0; w<THR/64; ++w) s += red[w*20 + threadIdx.x];
    atomicAdd(stage + (blockIdx.x & (SLOTS-1))*32 + threadIdx.x, s);
  }
}

// Gather the 32 slot partials of a stage into raw[20] (LDS).
__device__ __forceinline__ void sum_slots(const float* __restrict__ stage, float* raw){
  if(threadIdx.x < 20){
    float s = 0.f;
    #pragma unroll
    for(int j=0;j<SLOTS;++j) s += stage[j*32 + (int)threadIdx.x];
    raw[threadIdx.x] = s;
  }
  __syncthreads();
}

// ---- K1: read x (AoS f32), transpose to SoA fp16 zbuf, stage-0 stats ----
__global__ __launch_bounds__(THR)
void k_init(const float* __restrict__ x, h4* __restrict__ zbuf,
            float* __restrict__ stats){
  const int tid = blockIdx.x*THR + threadIdx.x;
  float acc[20];
  #pragma unroll
  for(int k=0;k<20;++k) acc[k]=0.f;
  #pragma unroll 2
  for(int g=0; g<GPT; ++g){
    const int G = tid + g*TOT;
    union { float4 v[5]; float f[20]; } u;
    const float4* xp = (const float4*)x + (size_t)G*5;
    #pragma unroll
    for(int q=0;q<5;++q) u.v[q] = xp[q];
    float4 z[5];
    #pragma unroll
    for(int c=0;c<5;++c) z[c] = make_float4(u.f[c], u.f[5+c], u.f[10+c], u.f[15+c]);
    #pragma unroll
    for(int c=0;c<5;++c){
      h4 hz = f4_to_h4(z[c]);
      zbuf[c*M4Q + G] = hz;
      z[c] = h4_to_f4(hz);           // stats on the rounded values (consistency)
    }
    acc_stats(z, acc);
  }
  reduce_slots(acc, stats + 0*SSTR);
}

// ---- K2 (x4): stats of h = relu(F1 z) ----
__global__ __launch_bounds__(THR)
void k_statsH(const h4* __restrict__ zbuf, float* __restrict__ stats,
              const float* __restrict__ lins_w, const float* __restrict__ bn_g,
              const float* __restrict__ bn_b, int b){
  const int i = 2*b, j = i+1;
  __shared__ float raw[20];
  __shared__ float F1s[30];
  sum_slots(stats + i*SSTR, raw);
  if(threadIdx.x < 5)
    fold_generic(raw, lins_w+25*i, bn_g+5*i, bn_b+5*i, (int)threadIdx.x,
                 1.0f/(float)NROWS, &F1s[threadIdx.x*5], &F1s[25+threadIdx.x]);
  __syncthreads();
  float f1[30];
  #pragma unroll
  for(int k=0;k<30;++k) f1[k] = F1s[k];
  const int tid = blockIdx.x*THR + threadIdx.x;
  float acc[20];
  #pragma unroll
  for(int k=0;k<20;++k) acc[k]=0.f;
  #pragma unroll 2
  for(int g=0; g<GPT; ++g){
    const int G = tid + g*TOT;
    float4 z[5], h[5];
    #pragma unroll
    for(int c=0;c<5;++c) z[c] = h4_to_f4(zbuf[c*M4Q + G]);
    #pragma unroll
    for(int c=0;c<5;++c){
      float4 u = mk4(f1[25+c]);
      #pragma unroll
      for(int d=0;d<5;++d) u = fma44(f1[c*5+d], z[d], u);
      h[c] = relu4(u);
    }
    acc_stats(h, acc);
  }
  reduce_slots(acc, stats + j*SSTR);
}

// ---- K3 (x4): z' = relu(F2 relu(F1 z) + SW z + c'), write z' (fp16), stats ----
__global__ __launch_bounds__(THR)
void k_updateZ(h4* __restrict__ zbuf, float* __restrict__ stats,
               const float* __restrict__ lins_w, const float* __restrict__ bn_g,
               const float* __restrict__ bn_b, const float* __restrict__ skips_w,
               const float* __restrict__ skips_b, int b){
  const int i = 2*b, j = i+1;
  __shared__ float rawA[20], rawB[20];
  __shared__ float F1s[30], F2s[30], SWs[25];
  sum_slots(stats + i*SSTR, rawA);
  sum_slots(stats + j*SSTR, rawB);
  if(threadIdx.x < 5){
    fold_generic(rawA, lins_w+25*i, bn_g+5*i, bn_b+5*i, (int)threadIdx.x,
                 1.0f/(float)NROWS, &F1s[threadIdx.x*5], &F1s[25+threadIdx.x]);
    fold_generic(rawB, lins_w+25*j, bn_g+5*j, bn_b+5*j, (int)threadIdx.x,
                 1.0f/(float)NROWS, &F2s[threadIdx.x*5], &F2s[25+threadIdx.x]);
    F2s[25+threadIdx.x] += skips_b[5*b + threadIdx.x];   // merge skip bias
  }
  if(threadIdx.x >= 64 && threadIdx.x < 89)
    SWs[threadIdx.x-64] = skips_w[25*b + (threadIdx.x-64)];
  __syncthreads();
  float f1[30], f2[30], sw[25];
  #pragma unroll
  for(int k=0;k<30;++k){ f1[k]=F1s[k]; f2[k]=F2s[k]; }
  #pragma unroll
  for(int k=0;k<25;++k) sw[k]=SWs[k];
  const int tid = blockIdx.x*THR + threadIdx.x;
  float acc[20];
  #pragma unroll
  for(int k=0;k<20;++k) acc[k]=0.f;
  #pragma unroll 2
  for(int g=0; g<GPT; ++g){
    const int G = tid + g*TOT;
    float4 z[5], h[5], t[5];
    #pragma unroll
    for(int c=0;c<5;++c) z[c] = h4_to_f4(zbuf[c*M4Q + G]);
    #pragma unroll
    for(int c=0;c<5;++c){
      float4 u = mk4(f1[25+c]);
      #pragma unroll
      for(int d=0;d<5;++d) u = fma44(f1[c*5+d], z[d], u);
      h[c] = relu4(u);
    }
    #pragma unroll
    for(int c=0;c<5;++c){
      float4 u = mk4(f2[25+c]);
      #pragma unroll
      for(int d=0;d<5;++d){
        u = fma44(f2[c*5+d], h[d], u);
        u = fma44(sw[c*5+d], z[d], u);
      }
      t[c] = relu4(u);
    }
    #pragma unroll
    for(int c=0;c<5;++c){
      h4 hz = f4_to_h4(t[c]);
      zbuf[c*M4Q + G] = hz;
      t[c] = h4_to_f4(hz);            // stats on the rounded values
    }
    acc_stats(t, acc);
  }
  reduce_slots(acc, stats + (i+2)*SSTR);
}

// ---- K4: fold lin9+bn9, apply lin10, write out (f32) ----
__global__ __launch_bounds__(THR)
void k_final(const h4* __restrict__ zbuf, const float* __restrict__ stats,
             const float* __restrict__ lin9_w, const float* __restrict__ bn9_g,
             const float* __restrict__ bn9_b, const float* __restrict__ lin10_w,
             const float* __restrict__ lin10_b, float* __restrict__ out){
  __shared__ float raw[20];
  __shared__ float A9c[12];
  sum_slots(stats + 8*SSTR, raw);
  if(threadIdx.x < 2)
    fold_generic(raw, lin9_w, bn9_g, bn9_b, (int)threadIdx.x,
                 1.0f/(float)NROWS, &A9c[threadIdx.x*5], &A9c[10+threadIdx.x]);
  __syncthreads();
  float f9[12];
  #pragma unroll
  for(int k=0;k<12;++k) f9[k] = A9c[k];
  const float w10a = lin10_w[0], w10b = lin10_w[1], b10 = lin10_b[0];
  const int tid = blockIdx.x*THR + threadIdx.x;
  #pragma unroll 2
  for(int g=0; g<GPT; ++g){
    const int G = tid + g*TOT;
    float4 z[5];
    #pragma unroll
    for(int c=0;c<5;++c) z[c] = h4_to_f4(zbuf[c*M4Q + G]);
    float4 u0 = mk4(f9[10]), u1 = mk4(f9[11]);
    #pragma unroll
    for(int d=0;d<5;++d){ u0 = fma44(f9[d], z[d], u0); u1 = fma44(f9[5+d], z[d], u1); }
    u0 = relu4(u0); u1 = relu4(u1);
    float4 o = mk4(b10);
    o = fma44(w10a, u0, o);
    o = fma44(w10b, u1, o);
    ((float4*)out)[G] = o;
  }
}

// ---- fallback (tiny ws): exact full-data recompute-from-x chain, f32 ----
__global__ __launch_bounds__(THR)
void k_fromx(const float* __restrict__ x, float* __restrict__ stats,
             const float* __restrict__ lins_w, const float* __restrict__ bn_g,
             const float* __restrict__ bn_b, const float* __restrict__ skips_w,
             const float* __restrict__ skips_b, const float* __restrict__ lin9_w,
             const float* __restrict__ bn9_g, const float* __restrict__ bn9_b,
             const float* __restrict__ lin10_w, const float* __restrict__ lin10_b,
             float* __restrict__ out, int target, int do_final){
  __shared__ float rawAll[9][20];
  __shared__ float FA[8][30];
  __shared__ float SW[100];
  __shared__ float A9c[12];
  const int tix = threadIdx.x;
  const int nf = do_final ? 9 : target;
  if(tix < 20*nf){
    const int L = tix/20, k = tix%20;
    float s = 0.f;
    #pragma unroll
    for(int j=0;j<SLOTS;++j) s += stats[L*SSTR + j*32 + k];
    rawAll[L][k] = s;
  }
  __syncthreads();
  const int nlay = do_final ? 8 : (target < 8 ? target : 8);
  if(tix < 5*nlay){
    const int L = tix/5, c = tix%5;
    fold_generic(&rawAll[L][0], lins_w+25*L, bn_g+5*L, bn_b+5*L, c,
                 1.0f/(float)NROWS, &FA[L][c*5], &FA[L][25+c]);
    if(L & 1) FA[L][25+c] += skips_b[(L>>1)*5 + c];
  } else if(tix >= 64 && tix < 164){
    SW[tix-64] = skips_w[tix-64];
  }
  if(do_final && tix >= 40 && tix < 42){
    const int c = tix-40;
    fold_generic(&rawAll[8][0], lin9_w, bn9_g, bn9_b, c,
                 1.0f/(float)NROWS, &A9c[c*5], &A9c[10+c]);
  }
  __syncthreads();
  float w10a=0.f, w10b=0.f, b10=0.f;
  if(do_final){ w10a = lin10_w[0]; w10b = lin10_w[1]; b10 = lin10_b[0]; }
  float acc[20];
  #pragma unroll
  for(int k=0;k<20;++k) acc[k]=0.f;
  const int gid = blockIdx.x*THR + tix;
  const int steps = do_final ? 8 : target;
  for(int t0=gid; t0<M4Q; t0+=TOT){
    union { float4 v[5]; float f[20]; } u;
    const float4* xp = (const float4*)x + (size_t)t0*5;
    #pragma unroll
    for(int q=0;q<5;++q) u.v[q] = xp[q];
    float4 z[5], h[5];
    #pragma unroll
    for(int c=0;c<5;++c) z[c] = make_float4(u.f[c], u.f[5+c], u.f[10+c], u.f[15+c]);
    #pragma unroll 1
    for(int s=1; s<=steps; ++s){
      const int L = s-1, b = L>>1;
      if(s & 1){
        #pragma unroll
        for(int c=0;c<5;++c){
          float4 t2 = mk4(FA[L][25+c]);
          #pragma unroll
          for(int d=0;d<5;++d) t2 = fma44(FA[L][c*5+d], z[d], t2);
          h[c] = relu4(t2);
        }
      } else {
        float4 zn[5];
        #pragma unroll
        for(int c=0;c<5;++c){
          float4 t2 = mk4(FA[L][25+c]);
          #pragma unroll
          for(int d=0;d<5;++d){
            t2 = fma44(FA[L][c*5+d], h[d], t2);
            t2 = fma44(SW[b*25+c*5+d], z[d], t2);
          }
          zn[c] = relu4(t2);
        }
        #pragma unroll
        for(int c=0;c<5;++c) z[c] = zn[c];
      }
    }
    if(do_final){
      float4 u0 = mk4(A9c[10]), u1 = mk4(A9c[11]);
      #pragma unroll
      for(int d=0;d<5;++d){ u0 = fma44(A9c[d], z[d], u0); u1 = fma44(A9c[5+d], z[d], u1); }
      u0 = relu4(u0); u1 = relu4(u1);
      float4 o = mk4(b10);
      o = fma44(w10a, u0, o);
      o = fma44(w10b, u1, o);
      ((float4*)out)[t0] = o;
    } else {
      if(steps & 1) acc_stats(h, acc);
      else          acc_stats(z, acc);
    }
  }
  if(!do_final) reduce_slots(acc, stats + target*SSTR);
}

extern "C" void kernel_launch(void* const* d_in, const int* in_sizes, int n_in,
                              void* d_out, int out_size, void* d_ws, size_t ws_size,
                              hipStream_t stream){
  (void)in_sizes; (void)n_in; (void)out_size;
  const float* x       = (const float*)d_in[0];
  const float* lins_w  = (const float*)d_in[1];
  // d_in[2] = lins_b: cancels inside BN, unused
  const float* skips_w = (const float*)d_in[3];
  const float* skips_b = (const float*)d_in[4];
  const float* bn_g    = (const float*)d_in[5];
  const float* bn_b    = (const float*)d_in[6];
  const float* lin9_w  = (const float*)d_in[7];
  // d_in[8] = lin9_b: cancels inside BN, unused
  const float* bn9_g   = (const float*)d_in[9];
  const float* bn9_b   = (const float*)d_in[10];
  const float* lin10_w = (const float*)d_in[11];
  const float* lin10_b = (const float*)d_in[12];
  float* out = (float*)d_out;

  if(ws_size >= ZBYTES_H + (size_t)STATS_BYTES){
    h4*    zbuf  = (h4*)d_ws;
    float* stats = (float*)((char*)d_ws + ZBYTES_H);
    hipMemsetAsync(stats, 0, STATS_BYTES, stream);
    k_init<<<BLK, THR, 0, stream>>>(x, zbuf, stats);
    for(int b=0;b<4;++b){
      k_statsH <<<BLK, THR, 0, stream>>>(zbuf, stats, lins_w, bn_g, bn_b, b);
      k_updateZ<<<BLK, THR, 0, stream>>>(zbuf, stats, lins_w, bn_g, bn_b,
                                         skips_w, skips_b, b);
    }
    k_final<<<BLK, THR, 0, stream>>>(zbuf, stats, lin9_w, bn9_g, bn9_b,
                                     lin10_w, lin10_b, out);
  } else {
    float* stats = (float*)d_ws;
    hipMemsetAsync(stats, 0, STATS_BYTES, stream);
    for(int s=0; s<=8; ++s)
      k_fromx<<<BLK, THR, 0, stream>>>(x, stats, lins_w, bn_g, bn_b, skips_w,
                                       skips_b, lin9_w, bn9_g, bn9_b, lin10_w,
                                       lin10_b, out, s, 0);
    k_fromx<<<BLK, THR, 0, stream>>>(x, stats, lins_w, bn_g, bn_b, skips_w,
                                     skips_b, lin9_w, bn9_g, bn9_b, lin10_w,
                                     lin10_b, out, 8, 1);
  }
}